// Round 7
// baseline (186.700 us; speedup 1.0000x reference)
//
#include <hip/hip_runtime.h>
#include <stdint.h>

#define L 21
#define C0 32
#define C1 32
#define IN_DIM 7
#define GHIST 256
#define BPAD 256  // bucket padding -> every 256-slot chunk is layer-uniform

// ---------------- K1: per-block histogram of idx ----------------
__global__ __launch_bounds__(256) void k_hist(const int* __restrict__ idx, int E,
                                              int* __restrict__ blockCounts) {
  __shared__ int h[L];
  int tid = threadIdx.x;
  if (tid < L) h[tid] = 0;
  __syncthreads();
  int per = (E + GHIST - 1) / GHIST;
  int s = blockIdx.x * per;
  int e = min(E, s + per);
  for (int i = s + tid; i < e; i += blockDim.x)
    atomicAdd(&h[idx[i]], 1);
  __syncthreads();
  if (tid < L) blockCounts[blockIdx.x * L + tid] = h[tid];
}

// ---------------- K2: totals, 256-padded bases, per-block cursors -------------
__global__ __launch_bounds__(256) void k_scan(const int* __restrict__ blockCounts,
                                              int* __restrict__ cursor,
                                              int* __restrict__ endArr,
                                              int* __restrict__ baseArr) {
  __shared__ int tot[L];
  __shared__ int base[L + 1];
  int tid = threadIdx.x;
  if (tid < L) {
    int s = 0;
#pragma unroll 8
    for (int b = 0; b < GHIST; b++) s += blockCounts[b * L + tid];
    tot[tid] = s;
  }
  __syncthreads();
  if (tid == 0) {
    int a = 0;
    for (int l = 0; l < L; l++) { base[l] = a; a += (tot[l] + BPAD - 1) & ~(BPAD - 1); }
    base[L] = a;
  }
  __syncthreads();
  if (tid < L) {
    int a = base[tid];
#pragma unroll 8
    for (int b = 0; b < GHIST; b++) {
      cursor[b * L + tid] = a;
      a += blockCounts[b * L + tid];
    }
    endArr[tid] = base[tid] + tot[tid];
  }
  if (tid <= L) baseArr[tid] = base[tid];
}

// ---------------- K3: scatter edge ids + gather input rows (fused) ------------
__global__ __launch_bounds__(256) void k_scatter(const int* __restrict__ idx,
                                                 const float* __restrict__ inp, int E,
                                                 const int* __restrict__ cursor,
                                                 int* __restrict__ perm,
                                                 float* __restrict__ xb) {
  __shared__ int cur[L];
  int tid = threadIdx.x;
  if (tid < L) cur[tid] = cursor[blockIdx.x * L + tid];
  __syncthreads();
  int per = (E + GHIST - 1) / GHIST;
  int s = blockIdx.x * per;
  int e = min(E, s + per);
  for (int i = s + tid; i < e; i += blockDim.x) {
    int l = idx[i];
    int pos = atomicAdd(&cur[l], 1);
    perm[pos] = i;
    const float* row = inp + (size_t)i * IN_DIM;
    float4 a, b;
    a.x = row[0]; a.y = row[1]; a.z = row[2]; a.w = row[3];
    b.x = row[4]; b.y = row[5]; b.z = row[6]; b.w = 0.f;
    float4* dst = (float4*)(xb + (size_t)pos * 8);
    dst[0] = a;
    dst[1] = b;
  }
}

// ---------------- K4: compute. Block-uniform l; VECTOR-path weight streaming;
// barrier-free per-wave LDS transpose epilogue.
template <bool USE_XB>
__global__ __launch_bounds__(256) void k_compute(const float* __restrict__ xb,
                                                 const float* __restrict__ inp,
                                                 const float* __restrict__ W0g,
                                                 const float* __restrict__ b0g,
                                                 const float* __restrict__ W1g,
                                                 const float* __restrict__ b1g,
                                                 const int* __restrict__ perm,
                                                 const int* __restrict__ baseArr,
                                                 const int* __restrict__ endArr,
                                                 float* __restrict__ out) {
  int T = threadIdx.x;
  int lane = T & 63;
  int blockbase = blockIdx.x << 8;

  // derive this block's layer from baseArr (blocks never straddle buckets)
  int bv = baseArr[lane <= L ? lane : L];
  unsigned long long m = __ballot((lane <= L) && (blockbase >= bv));
  int l = __popcll(m) - 1;
  if (l >= L) return;  // past all data (uniform across block)
  l = __builtin_amdgcn_readfirstlane(l);
  int end = __builtin_amdgcn_readfirstlane(endArr[l]);

  int slot = blockbase + T;

  // ---- load input row (padding slots read garbage; never stored) ----
  float x[IN_DIM];
  if (USE_XB) {
    const float4* xrow = (const float4*)(xb + (size_t)slot * 8);
    float4 xa = xrow[0], xc = xrow[1];
    x[0] = xa.x; x[1] = xa.y; x[2] = xa.z; x[3] = xa.w;
    x[4] = xc.x; x[5] = xc.y; x[6] = xc.z;
  } else {
    int p0 = slot < end ? perm[slot] : 0;
    const float* row = inp + (size_t)p0 * IN_DIM;
#pragma unroll
    for (int k = 0; k < IN_DIM; k++) x[k] = row[k];
  }

  // Weights on the VECTOR memory path: opaque asm makes the pointers
  // un-provably-uniform, so the compiler emits global_load (vmcnt-pipelined,
  // out-of-order, L2-hot) instead of s_load chains (lgkmcnt full-drain,
  // scalar-K$ cold misses every block). Wave-uniform addr -> 1 txn/load.
  uintptr_t w0a = (uintptr_t)(W0g + l * (IN_DIM * C0));
  uintptr_t w1a = (uintptr_t)(W1g + l * (C0 * C1));
  asm volatile("" : "+v"(w0a), "+v"(w1a));
  const float* w0 = (const float*)w0a;
  const float* w1 = (const float*)w1a;
  const float* B0 = b0g + l * C0;  // biases: 256 B, scalar path is fine
  const float* B1 = b1g + l * C1;

  float h[C0];
#pragma unroll
  for (int c = 0; c < C0; c++) h[c] = B0[c];
#pragma unroll
  for (int k = 0; k < IN_DIM; k++) {
#pragma unroll
    for (int c = 0; c < C0; c++) h[c] = fmaf(x[k], w0[k * C0 + c], h[c]);
  }
#pragma unroll
  for (int c = 0; c < C0; c++) h[c] = h[c] >= 0.f ? h[c] : 0.2f * h[c];

  float o[C1];
#pragma unroll
  for (int c = 0; c < C1; c++) o[c] = B1[c];
#pragma unroll
  for (int k = 0; k < C0; k++) {
#pragma unroll
    for (int c = 0; c < C1; c++) o[c] = fmaf(h[k], w1[k * C1 + c], o[c]);
  }
#pragma unroll
  for (int c = 0; c < C1; c++) o[c] = o[c] >= 0.f ? o[c] : 0.2f * o[c];

  // ---- per-wave transpose tile (no cross-wave sharing -> no barriers) ----
  __shared__ float obuf[4 * 64 * 32];
  float* tile = &obuf[(T >> 6) * (64 * 32)];
  // write own row, XOR-swizzled (keeps 16B alignment; 2-way banks = free)
#pragma unroll
  for (int cq = 0; cq < 32; cq += 4) {
    int ad = lane * 32 + (cq ^ ((lane & 7) << 2));
    float4 v = {o[cq], o[cq + 1], o[cq + 2], o[cq + 3]};
    *(float4*)&tile[ad] = v;
  }
  // read columns: 8 lanes per row -> 128B contiguous global bursts per row
  int wavebase = blockbase + (T >> 6) * 64;
  int q = (lane & 7) * 4;
  int rbase = lane >> 3;
#pragma unroll
  for (int step = 0; step < 8; step++) {
    int row = step * 8 + rbase;
    int slot_r = wavebase + row;
    if (slot_r < end) {
      int p = perm[slot_r];  // 8-lane broadcast, coalescer merges
      int sw = (row & 7) << 2;
      float4 v = *(const float4*)&tile[row * 32 + (q ^ sw)];
      *(float4*)(out + (size_t)p * C1 + q) = v;
    }
  }
}

extern "C" void kernel_launch(void* const* d_in, const int* in_sizes, int n_in,
                              void* d_out, int out_size, void* d_ws, size_t ws_size,
                              hipStream_t stream) {
  const float* inp = (const float*)d_in[0];
  const int* idx   = (const int*)d_in[1];
  const float* W0  = (const float*)d_in[2];
  const float* b0  = (const float*)d_in[3];
  const float* W1  = (const float*)d_in[4];
  const float* b1  = (const float*)d_in[5];
  float* out = (float*)d_out;
  int E = in_sizes[1];

  int nBlk = (E + 255) / 256 + L;  // upper bound on padded 256-chunks
  size_t slots = (size_t)nBlk * 256;

  int* ws = (int*)d_ws;
  int* blockCounts = ws;                       // GHIST*L
  int* cursor      = blockCounts + GHIST * L;  // GHIST*L
  int* endArr      = cursor + GHIST * L;       // L
  int* baseArr     = endArr + L;               // L+1
  int* perm        = baseArr + (L + 1);        // slots
  size_t ints = (size_t)2 * GHIST * L + L + (L + 1) + slots;
  ints = (ints + 3) & ~(size_t)3;              // 16B-align xb
  float* xb = (float*)(ws + ints);             // slots * 8 floats
  size_t need = ints * 4 + slots * 8 * 4;
  bool use_xb = ws_size >= need;

  k_hist<<<GHIST, 256, 0, stream>>>(idx, E, blockCounts);
  k_scan<<<1, 256, 0, stream>>>(blockCounts, cursor, endArr, baseArr);
  k_scatter<<<GHIST, 256, 0, stream>>>(idx, inp, E, cursor, perm, xb);

  if (use_xb) {
    k_compute<true><<<nBlk, 256, 0, stream>>>(xb, inp, W0, b0, W1, b1,
                                              perm, baseArr, endArr, out);
  } else {
    k_compute<false><<<nBlk, 256, 0, stream>>>(nullptr, inp, W0, b0, W1, b1,
                                               perm, baseArr, endArr, out);
  }
}

// Round 8
// 92.185 us; speedup vs baseline: 2.0253x; 2.0253x over previous
//
#include <hip/hip_runtime.h>

#define L 21
#define C0 32
#define C1 32
#define IN_DIM 7
#define GHIST 256
#define BPAD 256  // bucket padding -> every 256-slot chunk is layer-uniform
#define NW (IN_DIM * C0 + C0 + C0 * C1 + C1)  // 1312 floats of per-layer params

// ---------------- K1: per-block histogram of idx ----------------
__global__ __launch_bounds__(256) void k_hist(const int* __restrict__ idx, int E,
                                              int* __restrict__ blockCounts) {
  __shared__ int h[L];
  int tid = threadIdx.x;
  if (tid < L) h[tid] = 0;
  __syncthreads();
  int per = (E + GHIST - 1) / GHIST;
  int s = blockIdx.x * per;
  int e = min(E, s + per);
  for (int i = s + tid; i < e; i += blockDim.x)
    atomicAdd(&h[idx[i]], 1);
  __syncthreads();
  if (tid < L) blockCounts[blockIdx.x * L + tid] = h[tid];
}

// ---------------- K2: totals, 256-padded bases, per-block cursors -------------
__global__ __launch_bounds__(256) void k_scan(const int* __restrict__ blockCounts,
                                              int* __restrict__ cursor,
                                              int* __restrict__ endArr,
                                              int* __restrict__ baseArr) {
  __shared__ int tot[L];
  __shared__ int base[L + 1];
  int tid = threadIdx.x;
  if (tid < L) {
    int s = 0;
#pragma unroll 8
    for (int b = 0; b < GHIST; b++) s += blockCounts[b * L + tid];
    tot[tid] = s;
  }
  __syncthreads();
  if (tid == 0) {
    int a = 0;
    for (int l = 0; l < L; l++) { base[l] = a; a += (tot[l] + BPAD - 1) & ~(BPAD - 1); }
    base[L] = a;
  }
  __syncthreads();
  if (tid < L) {
    int a = base[tid];
#pragma unroll 8
    for (int b = 0; b < GHIST; b++) {
      cursor[b * L + tid] = a;
      a += blockCounts[b * L + tid];
    }
    endArr[tid] = base[tid] + tot[tid];
  }
  if (tid <= L) baseArr[tid] = base[tid];
}

// ---------------- K3: scatter edge ids + gather input rows (fused) ------------
__global__ __launch_bounds__(256) void k_scatter(const int* __restrict__ idx,
                                                 const float* __restrict__ inp, int E,
                                                 const int* __restrict__ cursor,
                                                 int* __restrict__ perm,
                                                 float* __restrict__ xb) {
  __shared__ int cur[L];
  int tid = threadIdx.x;
  if (tid < L) cur[tid] = cursor[blockIdx.x * L + tid];
  __syncthreads();
  int per = (E + GHIST - 1) / GHIST;
  int s = blockIdx.x * per;
  int e = min(E, s + per);
  for (int i = s + tid; i < e; i += blockDim.x) {
    int l = idx[i];
    int pos = atomicAdd(&cur[l], 1);
    perm[pos] = i;
    const float* row = inp + (size_t)i * IN_DIM;
    float4 a, b;
    a.x = row[0]; a.y = row[1]; a.z = row[2]; a.w = row[3];
    b.x = row[4]; b.y = row[5]; b.z = row[6]; b.w = 0.f;
    float4* dst = (float4*)(xb + (size_t)pos * 8);
    dst[0] = a;
    dst[1] = b;
  }
}

// ---------------- K4: compute. Weights staged in LDS once per block;
// FMAs consume wave-uniform broadcast ds_reads (no per-block L2 stall chain).
// Barrier-free per-wave LDS transpose epilogue.
template <bool USE_XB>
__global__ __launch_bounds__(256) void k_compute(const float* __restrict__ xb,
                                                 const float* __restrict__ inp,
                                                 const float* __restrict__ W0g,
                                                 const float* __restrict__ b0g,
                                                 const float* __restrict__ W1g,
                                                 const float* __restrict__ b1g,
                                                 const int* __restrict__ perm,
                                                 const int* __restrict__ baseArr,
                                                 const int* __restrict__ endArr,
                                                 float* __restrict__ out) {
  int T = threadIdx.x;
  int lane = T & 63;
  int blockbase = blockIdx.x << 8;

  // derive this block's layer from baseArr (blocks never straddle buckets)
  int bv = baseArr[lane <= L ? lane : L];
  unsigned long long m = __ballot((lane <= L) && (blockbase >= bv));
  int l = __popcll(m) - 1;
  if (l >= L) return;  // uniform across block: sync-safe
  l = __builtin_amdgcn_readfirstlane(l);
  int end = __builtin_amdgcn_readfirstlane(endArr[l]);

  int slot = blockbase + T;

  // ---- issue input-row load early (overlaps weight staging) ----
  float x[IN_DIM];
  if (USE_XB) {
    const float4* xrow = (const float4*)(xb + (size_t)slot * 8);
    float4 xa = xrow[0], xc = xrow[1];
    x[0] = xa.x; x[1] = xa.y; x[2] = xa.z; x[3] = xa.w;
    x[4] = xc.x; x[5] = xc.y; x[6] = xc.z;
  } else {
    int p0 = slot < end ? perm[slot] : 0;
    const float* row = inp + (size_t)p0 * IN_DIM;
#pragma unroll
    for (int k = 0; k < IN_DIM; k++) x[k] = row[k];
  }

  // ---- stage this layer's parameters into LDS (coalesced, once per block) ----
  // layout: [0,224) w0 | [224,256) b0 | [256,1280) w1 | [1280,1312) b1
  __shared__ float wbuf[NW];
  {
    const float* s0 = W0g + l * (IN_DIM * C0);
    const float* s2 = W1g + l * (C0 * C1);
    if (T < IN_DIM * C0) wbuf[T] = s0[T];
    if (T < C0) wbuf[IN_DIM * C0 + T] = b0g[l * C0 + T];
#pragma unroll
    for (int r = 0; r < 4; r++) wbuf[256 + r * 256 + T] = s2[r * 256 + T];
    if (T < C1) wbuf[1280 + T] = b1g[l * C1 + T];
  }
  __syncthreads();
  const float4* lw0 = (const float4*)&wbuf[0];     // [k][c4] : 7 x 8
  const float*  lb0 = &wbuf[IN_DIM * C0];
  const float4* lw1 = (const float4*)&wbuf[256];   // [k][c4] : 32 x 8
  const float*  lb1 = &wbuf[1280];

  float h[C0];
#pragma unroll
  for (int c = 0; c < C0; c++) h[c] = lb0[c];
#pragma unroll
  for (int k = 0; k < IN_DIM; k++) {
#pragma unroll
    for (int c4 = 0; c4 < 8; c4++) {
      float4 w = lw0[k * 8 + c4];
      h[c4 * 4 + 0] = fmaf(x[k], w.x, h[c4 * 4 + 0]);
      h[c4 * 4 + 1] = fmaf(x[k], w.y, h[c4 * 4 + 1]);
      h[c4 * 4 + 2] = fmaf(x[k], w.z, h[c4 * 4 + 2]);
      h[c4 * 4 + 3] = fmaf(x[k], w.w, h[c4 * 4 + 3]);
    }
  }
#pragma unroll
  for (int c = 0; c < C0; c++) h[c] = h[c] >= 0.f ? h[c] : 0.2f * h[c];

  float o[C1];
#pragma unroll
  for (int c = 0; c < C1; c++) o[c] = lb1[c];
#pragma unroll
  for (int k = 0; k < C0; k++) {
#pragma unroll
    for (int c4 = 0; c4 < 8; c4++) {
      float4 w = lw1[k * 8 + c4];
      o[c4 * 4 + 0] = fmaf(h[k], w.x, o[c4 * 4 + 0]);
      o[c4 * 4 + 1] = fmaf(h[k], w.y, o[c4 * 4 + 1]);
      o[c4 * 4 + 2] = fmaf(h[k], w.z, o[c4 * 4 + 2]);
      o[c4 * 4 + 3] = fmaf(h[k], w.w, o[c4 * 4 + 3]);
    }
  }
#pragma unroll
  for (int c = 0; c < C1; c++) o[c] = o[c] >= 0.f ? o[c] : 0.2f * o[c];

  // ---- per-wave transpose tile (no cross-wave sharing -> no barriers) ----
  __shared__ float obuf[4 * 64 * 32];
  float* tile = &obuf[(T >> 6) * (64 * 32)];
#pragma unroll
  for (int cq = 0; cq < 32; cq += 4) {
    int ad = lane * 32 + (cq ^ ((lane & 7) << 2));
    float4 v = {o[cq], o[cq + 1], o[cq + 2], o[cq + 3]};
    *(float4*)&tile[ad] = v;
  }
  int wavebase = blockbase + (T >> 6) * 64;
  int q = (lane & 7) * 4;
  int rbase = lane >> 3;
#pragma unroll
  for (int step = 0; step < 8; step++) {
    int row = step * 8 + rbase;
    int slot_r = wavebase + row;
    if (slot_r < end) {
      int p = perm[slot_r];  // 8-lane broadcast, coalescer merges
      int sw = (row & 7) << 2;
      float4 v = *(const float4*)&tile[row * 32 + (q ^ sw)];
      *(float4*)(out + (size_t)p * C1 + q) = v;
    }
  }
}

extern "C" void kernel_launch(void* const* d_in, const int* in_sizes, int n_in,
                              void* d_out, int out_size, void* d_ws, size_t ws_size,
                              hipStream_t stream) {
  const float* inp = (const float*)d_in[0];
  const int* idx   = (const int*)d_in[1];
  const float* W0  = (const float*)d_in[2];
  const float* b0  = (const float*)d_in[3];
  const float* W1  = (const float*)d_in[4];
  const float* b1  = (const float*)d_in[5];
  float* out = (float*)d_out;
  int E = in_sizes[1];

  int nBlk = (E + 255) / 256 + L;  // upper bound on padded 256-chunks
  size_t slots = (size_t)nBlk * 256;

  int* ws = (int*)d_ws;
  int* blockCounts = ws;                       // GHIST*L
  int* cursor      = blockCounts + GHIST * L;  // GHIST*L
  int* endArr      = cursor + GHIST * L;       // L
  int* baseArr     = endArr + L;               // L+1
  int* perm        = baseArr + (L + 1);        // slots
  size_t ints = (size_t)2 * GHIST * L + L + (L + 1) + slots;
  ints = (ints + 3) & ~(size_t)3;              // 16B-align xb
  float* xb = (float*)(ws + ints);             // slots * 8 floats
  size_t need = ints * 4 + slots * 8 * 4;
  bool use_xb = ws_size >= need;

  k_hist<<<GHIST, 256, 0, stream>>>(idx, E, blockCounts);
  k_scan<<<1, 256, 0, stream>>>(blockCounts, cursor, endArr, baseArr);
  k_scatter<<<GHIST, 256, 0, stream>>>(idx, inp, E, cursor, perm, xb);

  if (use_xb) {
    k_compute<true><<<nBlk, 256, 0, stream>>>(xb, inp, W0, b0, W1, b1,
                                              perm, baseArr, endArr, out);
  } else {
    k_compute<false><<<nBlk, 256, 0, stream>>>(nullptr, inp, W0, b0, W1, b1,
                                               perm, baseArr, endArr, out);
  }
}